// Round 6
// baseline (483.243 us; speedup 1.0000x reference)
//
#include <hip/hip_runtime.h>
#include <hip/hip_bf16.h>

#define B_ 8
#define D_ 40
#define T_ 192
#define G_ 256
#define U_ 768   // 3*UNITS
#define H_ 256   // UNITS

typedef _Float16 half2_t __attribute__((ext_vector_type(2)));
typedef _Float16 half8_t __attribute__((ext_vector_type(8)));

__device__ inline float fdot2f(half2_t a, half2_t b, float c){
#if __has_builtin(__builtin_amdgcn_fdot2)
  return __builtin_amdgcn_fdot2(a, b, c, false);
#else
  return c + (float)a.x*(float)b.x + (float)a.y*(float)b.y;
#endif
}

__device__ inline float sigmoidf_(float x){
  return 1.0f/(1.0f+__expf(-x));
}
__device__ inline float tanhf_(float x){
  float ax = fabsf(x);
  float e = __expf(-2.0f*ax);
  float t = (1.0f-e)/(1.0f+e);
  return copysignf(t, x);
}

// ---------------- Kernel 1: single-channel interp + per-(b,d) mean ----------
__global__ __launch_bounds__(256) void k_interp(
    const float* __restrict__ times, const float* __restrict__ values,
    const float* __restrict__ meas, const float* __restrict__ grid,
    const float* __restrict__ ksic,
    float* __restrict__ y, float* __restrict__ w, float* __restrict__ ytr,
    float* __restrict__ mean){
  int bd = blockIdx.x;            // b*D_+d
  int b = bd / D_, d = bd % D_;
  int g = threadIdx.x;
  __shared__ float tt[T_], vv[T_], mm[T_];
  __shared__ float red[256];
  if (g < T_){
    tt[g] = times[bd*T_+g];
    vv[g] = values[bd*T_+g];
    mm[g] = meas[bd*T_+g];
  }
  __syncthreads();
  float alpha = log1pf(__expf(ksic[d]));   // softplus
  float tg = grid[b*G_+g];
  float nmin = 3.4e38f;
  for (int t=0;t<T_;t++){
    if (mm[t] > 0.0f){
      float dd = tt[t]-tg;
      nmin = fminf(nmin, dd*dd);
    }
  }
  float s1=0.f, sv1=0.f, s10=0.f, sv10=0.f;
  for (int t=0;t<T_;t++){
    if (mm[t] > 0.0f){
      float dd = tt[t]-tg;
      float n = dd*dd - nmin;               // >= 0
      float e1  = __expf(-alpha*n);
      float e10 = __expf(-10.0f*alpha*n);
      s1 += e1;  sv1 += e1*vv[t];
      s10 += e10; sv10 += e10*vv[t];
    }
  }
  float yv = sv1/s1;
  float wv = -alpha*nmin + __logf(s1);
  y[bd*G_+g]   = yv;
  w[bd*G_+g]   = wv;
  ytr[bd*G_+g] = sv10/s10;
  red[g] = yv;
  __syncthreads();
  for (int s=128;s>0;s>>=1){
    if (g<s) red[g]+=red[g+s];
    __syncthreads();
  }
  if (g==0) mean[bd] = red[0]*(1.0f/(float)G_);
}

// ---------------- Kernel 2: cross-channel interp + feats + x_proj -----------
__global__ __launch_bounds__(256) void k_cross(
    const float* __restrict__ y, const float* __restrict__ w,
    const float* __restrict__ ytr, const float* __restrict__ mean,
    const float* __restrict__ crossW, const float* __restrict__ Wx,
    const float* __restrict__ gru_b, const int* __restrict__ lens,
    float* __restrict__ xproj){
  int bg = blockIdx.x;              // b*G_+g
  int b = bg >> 8, g = bg & 255;
  if (g >= lens[b]) return;         // x_proj unused beyond length
  __shared__ float wd[D_], yd[D_], ytrd[D_], md[D_], cc[D_], feats[3*D_];
  __shared__ float wstat[2];
  int tid = threadIdx.x;
  if (tid < D_){
    int idx = (b*D_+tid)*G_+g;
    wd[tid]=w[idx]; yd[tid]=y[idx]; ytrd[tid]=ytr[idx]; md[tid]=mean[b*D_+tid];
  }
  __syncthreads();
  if (tid==0){
    float mx=-3.4e38f;
    for (int d2=0;d2<D_;d2++) mx = fmaxf(mx, wd[d2]);
    float s=0.f;
    for (int d2=0;d2<D_;d2++) s += __expf(wd[d2]-mx);
    wstat[0]=mx; wstat[1]=1.0f/s;
  }
  __syncthreads();
  if (tid<D_){
    float sw = __expf(wd[tid]-wstat[0])*wstat[1];
    cc[tid] = sw*(yd[tid]-md[tid]);
  }
  __syncthreads();
  if (tid<D_){
    float acc=0.f;
    for (int d2=0;d2<D_;d2++) acc += cc[d2]*crossW[d2*D_+tid];
    float rep = acc + md[tid];
    feats[tid]       = rep;                   // rep1
    feats[D_+tid]    = __expf(wd[tid]);       // intensity
    feats[2*D_+tid]  = ytrd[tid]-rep;         // y_trans - rep1
  }
  __syncthreads();
  for (int jj=0;jj<3;jj++){
    int j = tid + jj*256;
    float acc = gru_b[j];
    #pragma unroll 4
    for (int i=0;i<3*D_;i++) acc += feats[i]*Wx[i*U_+j];
    xproj[(size_t)bg*U_ + j] = acc;
  }
}

// ---------------- Kernel 3: demo MLP -> h0 ----------------------------------
__global__ __launch_bounds__(256) void k_demo(
    const float* __restrict__ demo, const float* __restrict__ W1,
    const float* __restrict__ b1, const float* __restrict__ W2,
    const float* __restrict__ b2, float* __restrict__ h0){
  __shared__ float dl[B_*16];
  __shared__ float hid[B_*H_];
  int u = threadIdx.x;
  if (u < B_*16) dl[u] = demo[u];
  __syncthreads();
  float acc[B_];
  #pragma unroll
  for (int b=0;b<B_;b++) acc[b]=b1[u];
  for (int i=0;i<16;i++){
    float w1 = W1[i*H_+u];
    #pragma unroll
    for (int b=0;b<B_;b++) acc[b] += dl[b*16+i]*w1;
  }
  #pragma unroll
  for (int b=0;b<B_;b++) hid[b*H_+u] = fmaxf(acc[b],0.f);
  __syncthreads();
  #pragma unroll
  for (int b=0;b<B_;b++) acc[b]=b2[u];
  for (int k=0;k<H_;k++){
    float w2 = W2[k*H_+u];
    #pragma unroll
    for (int b=0;b<B_;b++) acc[b] += hid[b*H_+k]*w2;
  }
  #pragma unroll
  for (int b=0;b<B_;b++) h0[b*H_+u]=acc[b];
}

// ---------------- Kernel 4: masked GRU (one block per batch) ----------------
// 512 threads, 8 waves. __launch_bounds__(512, 1): under EITHER documented
// semantics (min 1 wave/EU, or min 1 workgroup/CU = 8 waves/CU = 2 waves/SIMD)
// the VGPR cap is 256 (addressable max). Empirical ladder:
//   (256,1)->256 granted; (512)->128; (512,2)->128 (CUDA min-blocks semantics).
// Per-thread demand: 192 weight VGPRs + ~35 working < 256 -> no spill.
//   threads   0..255 (grpA): z-column j (128 regs) + h-col j rows   0..127 (64)
//   threads 256..511 (grpB): r-column j (128 regs) + h-col j rows 128..255 (64)
// h double-buffered f16 in LDS (broadcast ds_read_b128); partials via LDS;
// grpA does the gate update. 2 barriers/step.
__global__ __launch_bounds__(512, 1)
void k_gru(
    const float* __restrict__ Wh, const float* __restrict__ gru_b,
    const float* __restrict__ xproj, const float* __restrict__ h0,
    const int* __restrict__ lens, const float* __restrict__ outW,
    const float* __restrict__ outb, float* __restrict__ out){
  int b = blockIdx.x;
  int t = threadIdx.x;
  bool grpA = (t < H_);
  int j = grpA ? t : t - H_;
  int czr = grpA ? j : (H_ + j);       // z-col or r-col index
  int ch  = 2*H_ + j;                  // h-col index
  int k0  = grpA ? 0 : 128;            // h-half row offset

  __shared__ half8_t hbuf[2][H_/8];    // double-buffered h (f16 octets)
  __shared__ float sr[H_];             // r-gate dot partial (from grpB)
  __shared__ float sh1[H_];            // h-col second-half partial (from grpB)
  __shared__ float red[512];

  // ---- preload weights into registers (static indices, fully unrolled) ----
  half2_t wzr[128];
  #pragma unroll
  for (int k=0;k<128;k++){
    float a0 = Wh[(2*k)*U_ + czr];
    float a1 = Wh[(2*k+1)*U_ + czr];
    half2_t p; p.x=(_Float16)a0; p.y=(_Float16)a1; wzr[k]=p;
  }
  half2_t whh[64];
  #pragma unroll
  for (int k=0;k<64;k++){
    float a0 = Wh[(k0+2*k)*U_ + ch];
    float a1 = Wh[(k0+2*k+1)*U_ + ch];
    half2_t p; p.x=(_Float16)a0; p.y=(_Float16)a1; whh[k]=p;
  }
  float bzr = gru_b[U_ + czr];                  // brz (grpA) / brr (grpB)
  float bh  = grpA ? gru_b[U_ + ch] : 0.0f;     // brh counted once

  float hj = 0.0f;
  if (grpA){
    hj = h0[b*H_ + j];
    ((_Float16*)hbuf[0])[j] = (_Float16)hj;
  }
  int len = lens[b];
  const float* xbase = xproj + (size_t)b*G_*U_;
  __syncthreads();

  float xpz=0.f, xpr=0.f, xph=0.f;
  if (grpA){
    xpz = xbase[j]; xpr = xbase[H_+j]; xph = xbase[2*H_+j];
  }

  for (int g=0; g<len; g++){
    const half8_t* hcur = hbuf[g & 1];
    // prefetch next step's x (latency hides under dot loops)
    float nxz=0.f, nxr=0.f, nxh=0.f;
    if (grpA && (g+1 < len)){
      const float* xn = xbase + (size_t)(g+1)*U_;
      nxz = xn[j]; nxr = xn[H_+j]; nxh = xn[2*H_+j];
    }
    float a0=bzr, a1=0.f, a2=0.f, a3=0.f;   // z/r column accum
    float c0=bh,  c1=0.f, c2=0.f, c3=0.f;   // h half-column accum
    #pragma unroll
    for (int kk=0;kk<32;kk++){
      half8_t hv = hcur[kk];                 // ds_read_b128 broadcast
      half2_t p0 = {hv[0],hv[1]};
      half2_t p1 = {hv[2],hv[3]};
      half2_t p2 = {hv[4],hv[5]};
      half2_t p3 = {hv[6],hv[7]};
      a0 = fdot2f(p0, wzr[4*kk+0], a0);
      a1 = fdot2f(p1, wzr[4*kk+1], a1);
      a2 = fdot2f(p2, wzr[4*kk+2], a2);
      a3 = fdot2f(p3, wzr[4*kk+3], a3);
    }
    const half8_t* hh = hcur + (grpA ? 0 : 16);   // wave-uniform offset
    #pragma unroll
    for (int kk=0;kk<16;kk++){
      half8_t hv = hh[kk];
      half2_t p0 = {hv[0],hv[1]};
      half2_t p1 = {hv[2],hv[3]};
      half2_t p2 = {hv[4],hv[5]};
      half2_t p3 = {hv[6],hv[7]};
      c0 = fdot2f(p0, whh[4*kk+0], c0);
      c1 = fdot2f(p1, whh[4*kk+1], c1);
      c2 = fdot2f(p2, whh[4*kk+2], c2);
      c3 = fdot2f(p3, whh[4*kk+3], c3);
    }
    float azr = (a0+a1)+(a2+a3);
    float ah  = (c0+c1)+(c2+c3);
    if (!grpA){ sr[j] = azr; sh1[j] = ah; }
    __syncthreads();
    if (grpA){
      float z    = sigmoidf_(xpz + azr);
      float r    = sigmoidf_(xpr + sr[j]);
      float cand = tanhf_(xph + r*(ah + sh1[j]));
      hj = z*hj + (1.0f-z)*cand;
      ((_Float16*)hbuf[(g+1)&1])[j] = (_Float16)hj;
    }
    __syncthreads();
    xpz = nxz; xpr = nxr; xph = nxh;
  }

  // out = sigmoid(h . outW + outb)
  red[t] = grpA ? hj*outW[j] : 0.0f;
  __syncthreads();
  for (int st=256;st>0;st>>=1){
    if (t<st) red[t]+=red[t+st];
    __syncthreads();
  }
  if (t==0) out[b] = sigmoidf_(red[0]+outb[0]);
}

extern "C" void kernel_launch(void* const* d_in, const int* in_sizes, int n_in,
                              void* d_out, int out_size, void* d_ws, size_t ws_size,
                              hipStream_t stream) {
  const float* demo   = (const float*)d_in[0];
  const float* times  = (const float*)d_in[1];
  const float* values = (const float*)d_in[2];
  const float* meas   = (const float*)d_in[3];
  const float* grid   = (const float*)d_in[4];
  const float* ksic   = (const float*)d_in[5];
  const float* crossW = (const float*)d_in[6];
  const float* dW1    = (const float*)d_in[7];
  const float* db1    = (const float*)d_in[8];
  const float* dW2    = (const float*)d_in[9];
  const float* db2    = (const float*)d_in[10];
  const float* gWx    = (const float*)d_in[11];
  const float* gWh    = (const float*)d_in[12];
  const float* gb     = (const float*)d_in[13];
  const float* outW   = (const float*)d_in[14];
  const float* outb   = (const float*)d_in[15];
  const int*   lens   = (const int*)d_in[16];
  float* out = (float*)d_out;

  float* ws   = (float*)d_ws;
  float* y    = ws;                        // B*D*G
  float* w    = y    + B_*D_*G_;
  float* ytr  = w    + B_*D_*G_;
  float* mean = ytr  + B_*D_*G_;
  float* h0   = mean + B_*D_;
  float* xprj = h0   + B_*H_;              // B*G*768

  k_interp<<<B_*D_, 256, 0, stream>>>(times, values, meas, grid, ksic, y, w, ytr, mean);
  k_demo  <<<1,     256, 0, stream>>>(demo, dW1, db1, dW2, db2, h0);
  k_cross <<<B_*G_, 256, 0, stream>>>(y, w, ytr, mean, crossW, gWx, gb, lens, xprj);
  k_gru   <<<B_,    512, 0, stream>>>(gWh, gb, xprj, h0, lens, outW, outb, out);
}

// Round 7
// 374.076 us; speedup vs baseline: 1.2918x; 1.2918x over previous
//
#include <hip/hip_runtime.h>
#include <hip/hip_bf16.h>

#define B_ 8
#define D_ 40
#define T_ 192
#define G_ 256
#define U_ 768   // 3*UNITS
#define H_ 256   // UNITS

typedef _Float16 half2_t __attribute__((ext_vector_type(2)));
typedef _Float16 half8_t __attribute__((ext_vector_type(8)));

__device__ inline float fdot2f(half2_t a, half2_t b, float c){
#if __has_builtin(__builtin_amdgcn_fdot2)
  return __builtin_amdgcn_fdot2(a, b, c, false);
#else
  return c + (float)a.x*(float)b.x + (float)a.y*(float)b.y;
#endif
}

__device__ inline float sigmoidf_(float x){
  return 1.0f/(1.0f+__expf(-x));
}
__device__ inline float tanhf_(float x){
  float ax = fabsf(x);
  float e = __expf(-2.0f*ax);
  float t = (1.0f-e)/(1.0f+e);
  return copysignf(t, x);
}

// ---------------- Kernel 1: single-channel interp + per-(b,d) mean ----------
__global__ __launch_bounds__(256) void k_interp(
    const float* __restrict__ times, const float* __restrict__ values,
    const float* __restrict__ meas, const float* __restrict__ grid,
    const float* __restrict__ ksic,
    float* __restrict__ y, float* __restrict__ w, float* __restrict__ ytr,
    float* __restrict__ mean){
  int bd = blockIdx.x;            // b*D_+d
  int b = bd / D_, d = bd % D_;
  int g = threadIdx.x;
  __shared__ float tt[T_], vv[T_], mm[T_];
  __shared__ float red[256];
  if (g < T_){
    tt[g] = times[bd*T_+g];
    vv[g] = values[bd*T_+g];
    mm[g] = meas[bd*T_+g];
  }
  __syncthreads();
  float alpha = log1pf(__expf(ksic[d]));   // softplus
  float tg = grid[b*G_+g];
  float nmin = 3.4e38f;
  for (int t=0;t<T_;t++){
    if (mm[t] > 0.0f){
      float dd = tt[t]-tg;
      nmin = fminf(nmin, dd*dd);
    }
  }
  float s1=0.f, sv1=0.f, s10=0.f, sv10=0.f;
  for (int t=0;t<T_;t++){
    if (mm[t] > 0.0f){
      float dd = tt[t]-tg;
      float n = dd*dd - nmin;               // >= 0
      float e1  = __expf(-alpha*n);
      float e10 = __expf(-10.0f*alpha*n);
      s1 += e1;  sv1 += e1*vv[t];
      s10 += e10; sv10 += e10*vv[t];
    }
  }
  float yv = sv1/s1;
  float wv = -alpha*nmin + __logf(s1);
  y[bd*G_+g]   = yv;
  w[bd*G_+g]   = wv;
  ytr[bd*G_+g] = sv10/s10;
  red[g] = yv;
  __syncthreads();
  for (int s=128;s>0;s>>=1){
    if (g<s) red[g]+=red[g+s];
    __syncthreads();
  }
  if (g==0) mean[bd] = red[0]*(1.0f/(float)G_);
}

// ---------------- Kernel 2: cross-channel interp + feats + x_proj -----------
__global__ __launch_bounds__(256) void k_cross(
    const float* __restrict__ y, const float* __restrict__ w,
    const float* __restrict__ ytr, const float* __restrict__ mean,
    const float* __restrict__ crossW, const float* __restrict__ Wx,
    const float* __restrict__ gru_b, const int* __restrict__ lens,
    float* __restrict__ xproj){
  int bg = blockIdx.x;              // b*G_+g
  int b = bg >> 8, g = bg & 255;
  if (g >= lens[b]) return;         // x_proj unused beyond length
  __shared__ float wd[D_], yd[D_], ytrd[D_], md[D_], cc[D_], feats[3*D_];
  __shared__ float wstat[2];
  int tid = threadIdx.x;
  if (tid < D_){
    int idx = (b*D_+tid)*G_+g;
    wd[tid]=w[idx]; yd[tid]=y[idx]; ytrd[tid]=ytr[idx]; md[tid]=mean[b*D_+tid];
  }
  __syncthreads();
  if (tid==0){
    float mx=-3.4e38f;
    for (int d2=0;d2<D_;d2++) mx = fmaxf(mx, wd[d2]);
    float s=0.f;
    for (int d2=0;d2<D_;d2++) s += __expf(wd[d2]-mx);
    wstat[0]=mx; wstat[1]=1.0f/s;
  }
  __syncthreads();
  if (tid<D_){
    float sw = __expf(wd[tid]-wstat[0])*wstat[1];
    cc[tid] = sw*(yd[tid]-md[tid]);
  }
  __syncthreads();
  if (tid<D_){
    float acc=0.f;
    for (int d2=0;d2<D_;d2++) acc += cc[d2]*crossW[d2*D_+tid];
    float rep = acc + md[tid];
    feats[tid]       = rep;                   // rep1
    feats[D_+tid]    = __expf(wd[tid]);       // intensity
    feats[2*D_+tid]  = ytrd[tid]-rep;         // y_trans - rep1
  }
  __syncthreads();
  for (int jj=0;jj<3;jj++){
    int j = tid + jj*256;
    float acc = gru_b[j];
    #pragma unroll 4
    for (int i=0;i<3*D_;i++) acc += feats[i]*Wx[i*U_+j];
    xproj[(size_t)bg*U_ + j] = acc;
  }
}

// ---------------- Kernel 3: demo MLP -> h0 ----------------------------------
__global__ __launch_bounds__(256) void k_demo(
    const float* __restrict__ demo, const float* __restrict__ W1,
    const float* __restrict__ b1, const float* __restrict__ W2,
    const float* __restrict__ b2, float* __restrict__ h0){
  __shared__ float dl[B_*16];
  __shared__ float hid[B_*H_];
  int u = threadIdx.x;
  if (u < B_*16) dl[u] = demo[u];
  __syncthreads();
  float acc[B_];
  #pragma unroll
  for (int b=0;b<B_;b++) acc[b]=b1[u];
  for (int i=0;i<16;i++){
    float w1 = W1[i*H_+u];
    #pragma unroll
    for (int b=0;b<B_;b++) acc[b] += dl[b*16+i]*w1;
  }
  #pragma unroll
  for (int b=0;b<B_;b++) hid[b*H_+u] = fmaxf(acc[b],0.f);
  __syncthreads();
  #pragma unroll
  for (int b=0;b<B_;b++) acc[b]=b2[u];
  for (int k=0;k<H_;k++){
    float w2 = W2[k*H_+u];
    #pragma unroll
    for (int b=0;b<B_;b++) acc[b] += hid[b*H_+k]*w2;
  }
  #pragma unroll
  for (int b=0;b<B_;b++) h0[b*H_+u]=acc[b];
}

// ---------------- Kernel 4: masked GRU (one block per batch) ----------------
// 1024 threads (16 waves). For a 16-wave block the VGPR cap is hardware-forced
// to 128 (4 waves/SIMD min x 128 = full 512-reg pool) -- no launch-bounds
// ambiguity (empirical: 512-thread blocks were capped at 128 by the compiler
// in R4-R6 regardless of hints; only 4-wave blocks ever got 256).
// Thread (p = t>>8, j = t&255) owns rows [64p,64p+64) of Wh columns
// {z_j, r_j, h_j}: 3 x 32 f16x2 = 96 weight VGPRs + ~30 working <= 128.
// p is wave-uniform -> LDS h reads stay wave-uniform broadcasts.
// Per step: 96 fdot2/thread -> partials in part[gate][p][j] (stride-4B in j,
// conflict-free) -> barrier -> t<256 sums 4 partials/gate, applies gates,
// writes f16 h double-buffer -> barrier.
__global__ __launch_bounds__(1024, 1)
void k_gru(
    const float* __restrict__ Wh, const float* __restrict__ gru_b,
    const float* __restrict__ xproj, const float* __restrict__ h0,
    const int* __restrict__ lens, const float* __restrict__ outW,
    const float* __restrict__ outb, float* __restrict__ out){
  int b = blockIdx.x;
  int t = threadIdx.x;
  int p = t >> 8;                      // quarter index (wave-uniform)
  int j = t & 255;                     // hidden unit
  int r0 = p*64;                       // first row of this thread's quarter

  __shared__ half8_t hbuf[2][H_/8];    // double-buffered h (f16 octets)
  __shared__ float part[3][4][H_];     // per-gate, per-quarter partials
  __shared__ float red[H_];

  // ---- preload weight quarters (static indices, fully unrolled) ----
  half2_t wz[32], wr[32], wh[32];
  #pragma unroll
  for (int k=0;k<32;k++){
    const float* rp0 = Wh + (size_t)(r0+2*k)*U_;
    const float* rp1 = rp0 + U_;
    half2_t a, c, e;
    a.x=(_Float16)rp0[j];       a.y=(_Float16)rp1[j];       wz[k]=a;
    c.x=(_Float16)rp0[H_+j];    c.y=(_Float16)rp1[H_+j];    wr[k]=c;
    e.x=(_Float16)rp0[2*H_+j];  e.y=(_Float16)rp1[2*H_+j];  wh[k]=e;
  }
  float brz=0.f, brr=0.f, brh=0.f, hj=0.f;
  if (p==0){
    brz = gru_b[U_+j]; brr = gru_b[U_+H_+j]; brh = gru_b[U_+2*H_+j];
    hj = h0[b*H_+j];
    ((_Float16*)hbuf[0])[j] = (_Float16)hj;
  }
  int len = lens[b];
  const float* xbase = xproj + (size_t)b*G_*U_;
  __syncthreads();

  for (int g=0; g<len; g++){
    // x-proj loads issue here (p0 only); latency hides under the dot phase,
    // values consumed after the barrier.
    float xpz=0.f, xpr=0.f, xph=0.f;
    if (p==0){
      const float* xr = xbase + (size_t)g*U_;
      xpz = xr[j]; xpr = xr[H_+j]; xph = xr[2*H_+j];
    }
    const half8_t* hcur = hbuf[g&1] + p*8;   // this quarter's 64 rows
    float az=0.f, ar=0.f, ah=0.f;            // 3 independent chains (ILP=3)
    #pragma unroll
    for (int k=0;k<8;k++){
      half8_t hv = hcur[k];                  // wave-uniform ds_read_b128
      half2_t q0={hv[0],hv[1]}, q1={hv[2],hv[3]};
      half2_t q2={hv[4],hv[5]}, q3={hv[6],hv[7]};
      az=fdot2f(q0,wz[4*k+0],az); ar=fdot2f(q0,wr[4*k+0],ar); ah=fdot2f(q0,wh[4*k+0],ah);
      az=fdot2f(q1,wz[4*k+1],az); ar=fdot2f(q1,wr[4*k+1],ar); ah=fdot2f(q1,wh[4*k+1],ah);
      az=fdot2f(q2,wz[4*k+2],az); ar=fdot2f(q2,wr[4*k+2],ar); ah=fdot2f(q2,wh[4*k+2],ah);
      az=fdot2f(q3,wz[4*k+3],az); ar=fdot2f(q3,wr[4*k+3],ar); ah=fdot2f(q3,wh[4*k+3],ah);
    }
    part[0][p][j]=az; part[1][p][j]=ar; part[2][p][j]=ah;   // conflict-free
    __syncthreads();
    if (t < H_){
      float sz = part[0][0][j]+part[0][1][j]+part[0][2][j]+part[0][3][j];
      float sr = part[1][0][j]+part[1][1][j]+part[1][2][j]+part[1][3][j];
      float sh = part[2][0][j]+part[2][1][j]+part[2][2][j]+part[2][3][j];
      float z    = sigmoidf_(xpz + sz + brz);
      float r    = sigmoidf_(xpr + sr + brr);
      float cand = tanhf_(xph + r*(sh + brh));
      hj = z*hj + (1.0f-z)*cand;
      ((_Float16*)hbuf[(g+1)&1])[j] = (_Float16)hj;
    }
    __syncthreads();
  }

  // out = sigmoid(h . outW + outb)
  if (t < H_) red[j] = hj*outW[j];
  __syncthreads();
  for (int st=128;st>0;st>>=1){
    if (t<st) red[t]+=red[t+st];
    __syncthreads();
  }
  if (t==0) out[b] = sigmoidf_(red[0]+outb[0]);
}

extern "C" void kernel_launch(void* const* d_in, const int* in_sizes, int n_in,
                              void* d_out, int out_size, void* d_ws, size_t ws_size,
                              hipStream_t stream) {
  const float* demo   = (const float*)d_in[0];
  const float* times  = (const float*)d_in[1];
  const float* values = (const float*)d_in[2];
  const float* meas   = (const float*)d_in[3];
  const float* grid   = (const float*)d_in[4];
  const float* ksic   = (const float*)d_in[5];
  const float* crossW = (const float*)d_in[6];
  const float* dW1    = (const float*)d_in[7];
  const float* db1    = (const float*)d_in[8];
  const float* dW2    = (const float*)d_in[9];
  const float* db2    = (const float*)d_in[10];
  const float* gWx    = (const float*)d_in[11];
  const float* gWh    = (const float*)d_in[12];
  const float* gb     = (const float*)d_in[13];
  const float* outW   = (const float*)d_in[14];
  const float* outb   = (const float*)d_in[15];
  const int*   lens   = (const int*)d_in[16];
  float* out = (float*)d_out;

  float* ws   = (float*)d_ws;
  float* y    = ws;                        // B*D*G
  float* w    = y    + B_*D_*G_;
  float* ytr  = w    + B_*D_*G_;
  float* mean = ytr  + B_*D_*G_;
  float* h0   = mean + B_*D_;
  float* xprj = h0   + B_*H_;              // B*G*768

  k_interp<<<B_*D_, 256, 0, stream>>>(times, values, meas, grid, ksic, y, w, ytr, mean);
  k_demo  <<<1,     256, 0, stream>>>(demo, dW1, db1, dW2, db2, h0);
  k_cross <<<B_*G_, 256, 0, stream>>>(y, w, ytr, mean, crossW, gWx, gb, lens, xprj);
  k_gru   <<<B_,   1024, 0, stream>>>(gWh, gb, xprj, h0, lens, outW, outb, out);
}

// Round 8
// 295.782 us; speedup vs baseline: 1.6338x; 1.2647x over previous
//
#include <hip/hip_runtime.h>
#include <hip/hip_bf16.h>

#define B_ 8
#define D_ 40
#define T_ 192
#define G_ 256
#define U_ 768   // 3*UNITS
#define H_ 256   // UNITS

typedef _Float16 half2_t __attribute__((ext_vector_type(2)));

__device__ inline float sigmoidf_(float x){
  return 1.0f/(1.0f+__expf(-x));
}
__device__ inline float tanhf_(float x){
  float ax = fabsf(x);
  float e = __expf(-2.0f*ax);
  float t = (1.0f-e)/(1.0f+e);
  return copysignf(t, x);
}
__device__ inline int sdot4(int a, int b, int c){
#if __has_builtin(__builtin_amdgcn_sdot4)
  return __builtin_amdgcn_sdot4(a, b, c, false);
#else
  int r = c;
  #pragma unroll
  for (int i=0;i<4;i++){
    int ai = (a << (24-8*i)) >> 24;
    int bi = (b << (24-8*i)) >> 24;
    r += ai*bi;
  }
  return r;
#endif
}
__device__ inline int pack4(int q0,int q1,int q2,int q3){
  return (q0&255) | ((q1&255)<<8) | ((q2&255)<<16) | ((q3&255)<<24);
}

// ---------------- Kernel 1: single-channel interp + per-(b,d) mean ----------
__global__ __launch_bounds__(256) void k_interp(
    const float* __restrict__ times, const float* __restrict__ values,
    const float* __restrict__ meas, const float* __restrict__ grid,
    const float* __restrict__ ksic,
    float* __restrict__ y, float* __restrict__ w, float* __restrict__ ytr,
    float* __restrict__ mean){
  int bd = blockIdx.x;            // b*D_+d
  int b = bd / D_, d = bd % D_;
  int g = threadIdx.x;
  __shared__ float tt[T_], vv[T_], mm[T_];
  __shared__ float red[256];
  if (g < T_){
    tt[g] = times[bd*T_+g];
    vv[g] = values[bd*T_+g];
    mm[g] = meas[bd*T_+g];
  }
  __syncthreads();
  float alpha = log1pf(__expf(ksic[d]));   // softplus
  float tg = grid[b*G_+g];
  float nmin = 3.4e38f;
  for (int t=0;t<T_;t++){
    if (mm[t] > 0.0f){
      float dd = tt[t]-tg;
      nmin = fminf(nmin, dd*dd);
    }
  }
  float s1=0.f, sv1=0.f, s10=0.f, sv10=0.f;
  for (int t=0;t<T_;t++){
    if (mm[t] > 0.0f){
      float dd = tt[t]-tg;
      float n = dd*dd - nmin;               // >= 0
      float e1  = __expf(-alpha*n);
      float e10 = __expf(-10.0f*alpha*n);
      s1 += e1;  sv1 += e1*vv[t];
      s10 += e10; sv10 += e10*vv[t];
    }
  }
  float yv = sv1/s1;
  float wv = -alpha*nmin + __logf(s1);
  y[bd*G_+g]   = yv;
  w[bd*G_+g]   = wv;
  ytr[bd*G_+g] = sv10/s10;
  red[g] = yv;
  __syncthreads();
  for (int s=128;s>0;s>>=1){
    if (g<s) red[g]+=red[g+s];
    __syncthreads();
  }
  if (g==0) mean[bd] = red[0]*(1.0f/(float)G_);
}

// ---------------- Kernel 2: cross-channel interp + feats + x_proj -----------
__global__ __launch_bounds__(256) void k_cross(
    const float* __restrict__ y, const float* __restrict__ w,
    const float* __restrict__ ytr, const float* __restrict__ mean,
    const float* __restrict__ crossW, const float* __restrict__ Wx,
    const float* __restrict__ gru_b, const int* __restrict__ lens,
    float* __restrict__ xproj){
  int bg = blockIdx.x;              // b*G_+g
  int b = bg >> 8, g = bg & 255;
  if (g >= lens[b]) return;         // x_proj unused beyond length
  __shared__ float wd[D_], yd[D_], ytrd[D_], md[D_], cc[D_], feats[3*D_];
  __shared__ float wstat[2];
  int tid = threadIdx.x;
  if (tid < D_){
    int idx = (b*D_+tid)*G_+g;
    wd[tid]=w[idx]; yd[tid]=y[idx]; ytrd[tid]=ytr[idx]; md[tid]=mean[b*D_+tid];
  }
  __syncthreads();
  if (tid==0){
    float mx=-3.4e38f;
    for (int d2=0;d2<D_;d2++) mx = fmaxf(mx, wd[d2]);
    float s=0.f;
    for (int d2=0;d2<D_;d2++) s += __expf(wd[d2]-mx);
    wstat[0]=mx; wstat[1]=1.0f/s;
  }
  __syncthreads();
  if (tid<D_){
    float sw = __expf(wd[tid]-wstat[0])*wstat[1];
    cc[tid] = sw*(yd[tid]-md[tid]);
  }
  __syncthreads();
  if (tid<D_){
    float acc=0.f;
    for (int d2=0;d2<D_;d2++) acc += cc[d2]*crossW[d2*D_+tid];
    float rep = acc + md[tid];
    feats[tid]       = rep;                   // rep1
    feats[D_+tid]    = __expf(wd[tid]);       // intensity
    feats[2*D_+tid]  = ytrd[tid]-rep;         // y_trans - rep1
  }
  __syncthreads();
  for (int jj=0;jj<3;jj++){
    int j = tid + jj*256;
    float acc = gru_b[j];
    #pragma unroll 4
    for (int i=0;i<3*D_;i++) acc += feats[i]*Wx[i*U_+j];
    xproj[(size_t)bg*U_ + j] = acc;
  }
}

// ---------------- Kernel 3: demo MLP -> h0 ----------------------------------
__global__ __launch_bounds__(256) void k_demo(
    const float* __restrict__ demo, const float* __restrict__ W1,
    const float* __restrict__ b1, const float* __restrict__ W2,
    const float* __restrict__ b2, float* __restrict__ h0){
  __shared__ float dl[B_*16];
  __shared__ float hid[B_*H_];
  int u = threadIdx.x;
  if (u < B_*16) dl[u] = demo[u];
  __syncthreads();
  float acc[B_];
  #pragma unroll
  for (int b=0;b<B_;b++) acc[b]=b1[u];
  for (int i=0;i<16;i++){
    float w1 = W1[i*H_+u];
    #pragma unroll
    for (int b=0;b<B_;b++) acc[b] += dl[b*16+i]*w1;
  }
  #pragma unroll
  for (int b=0;b<B_;b++) hid[b*H_+u] = fmaxf(acc[b],0.f);
  __syncthreads();
  #pragma unroll
  for (int b=0;b<B_;b++) acc[b]=b2[u];
  for (int k=0;k<H_;k++){
    float w2 = W2[k*H_+u];
    #pragma unroll
    for (int b=0;b<B_;b++) acc[b] += hid[b*H_+k]*w2;
  }
  #pragma unroll
  for (int b=0;b<B_;b++) h0[b*H_+u]=acc[b];
}

// ---------------- Kernel 4: masked GRU, int8-quantized weights --------------
// RF grant invariant (measured R3-R7): allocator gives each workgroup 256KB of
// RF (grant = 256 regs for 4-wave, 128 for 8-wave, 64 for 16-wave blocks),
// regardless of launch-bounds/waves-per-eu hints. f16 Wh (384KB) can never
// fit; int8 Wh (192KB) fits a 512-thread block's grant.
// Quantization: per-column symmetric s_w=max|col|/127; h quantized with fixed
// scale s_h=max(|h0|max,1)/127 (provable bound: |h_new|<=max(|h_old|,1) since
// z in (0,1), |cand|<=1). i32 dot accumulation is exact (v_dot4_i32_i8).
// Thread (p=t>>8, j=t&255) owns rows [128p,128p+128) of cols {z_j,r_j,h_j}:
// 96 dword weight regs + ~28 working <= 128 grant -> no spill.
__global__ __launch_bounds__(512, 1)
void k_gru(
    const float* __restrict__ Wh, const float* __restrict__ gru_b,
    const float* __restrict__ xproj, const float* __restrict__ h0,
    const int* __restrict__ lens, const float* __restrict__ outW,
    const float* __restrict__ outb, float* __restrict__ out){
  int b = blockIdx.x;
  int t = threadIdx.x;
  int p = t >> 8;                      // half index (wave-uniform)
  int j = t & 255;                     // hidden unit / column
  int r0 = p*128;                      // first row of this thread's half

  __shared__ int   hq[2][64];          // packed i8 h, double-buffered
  __shared__ int   parti[3][H_];       // p=1 dot partials (i32)
  __shared__ float wmax[3][2][H_];     // per-col half-maxes (prologue)
  __shared__ float red[H_];
  __shared__ float shs[2];             // [0]=inv_sh, [1]=s_h

  // ---- prologue pass 1: per-column abs-max (each half scans its rows) ----
  float m0=0.f, m1=0.f, m2=0.f;
  for (int k=0;k<128;k++){
    const float* row = Wh + (size_t)(r0+k)*U_;
    m0 = fmaxf(m0, fabsf(row[j]));
    m1 = fmaxf(m1, fabsf(row[H_+j]));
    m2 = fmaxf(m2, fabsf(row[2*H_+j]));
  }
  wmax[0][p][j]=m0; wmax[1][p][j]=m1; wmax[2][p][j]=m2;

  // ---- h0 + its abs-max (bound for the h scale) ----
  float hj = 0.f;
  if (t < H_){
    hj = h0[b*H_+j];
    red[j] = fabsf(hj);
  }
  __syncthreads();
  for (int st=128; st>0; st>>=1){
    if (t < st) red[t] = fmaxf(red[t], red[t+st]);
    __syncthreads();
  }
  if (t==0){
    float bound = fmaxf(red[0], 1.0f);
    shs[0] = 127.0f/bound;             // inv_sh
    shs[1] = bound/127.0f;             // s_h
  }
  __syncthreads();
  float inv_sh = shs[0];
  float s_h    = shs[1];

  // combined column maxes -> scales (identical in both halves)
  float cm0 = fmaxf(wmax[0][0][j], wmax[0][1][j]);
  float cm1 = fmaxf(wmax[1][0][j], wmax[1][1][j]);
  float cm2 = fmaxf(wmax[2][0][j], wmax[2][1][j]);
  float iw0 = (cm0>0.f)? 127.0f/cm0 : 0.f;
  float iw1 = (cm1>0.f)? 127.0f/cm1 : 0.f;
  float iw2 = (cm2>0.f)? 127.0f/cm2 : 0.f;
  float fz = (cm0*(1.0f/127.0f))*s_h;  // dequant factor per gate
  float fr = (cm1*(1.0f/127.0f))*s_h;
  float fh = (cm2*(1.0f/127.0f))*s_h;

  // ---- prologue pass 2: quantize + pack weights into registers ----
  int wq0[32], wq1[32], wq2[32];
  #pragma unroll
  for (int k=0;k<32;k++){
    int a0,a1,a2,a3, c0,c1,c2,c3, e0,e1,e2,e3;
    {
      const float* row = Wh + (size_t)(r0+4*k+0)*U_;
      a0=(int)rintf(row[j]*iw0); c0=(int)rintf(row[H_+j]*iw1); e0=(int)rintf(row[2*H_+j]*iw2);
    }
    {
      const float* row = Wh + (size_t)(r0+4*k+1)*U_;
      a1=(int)rintf(row[j]*iw0); c1=(int)rintf(row[H_+j]*iw1); e1=(int)rintf(row[2*H_+j]*iw2);
    }
    {
      const float* row = Wh + (size_t)(r0+4*k+2)*U_;
      a2=(int)rintf(row[j]*iw0); c2=(int)rintf(row[H_+j]*iw1); e2=(int)rintf(row[2*H_+j]*iw2);
    }
    {
      const float* row = Wh + (size_t)(r0+4*k+3)*U_;
      a3=(int)rintf(row[j]*iw0); c3=(int)rintf(row[H_+j]*iw1); e3=(int)rintf(row[2*H_+j]*iw2);
    }
    wq0[k]=pack4(a0,a1,a2,a3);
    wq1[k]=pack4(c0,c1,c2,c3);
    wq2[k]=pack4(e0,e1,e2,e3);
  }

  float brz=0.f, brr=0.f, brh=0.f;
  if (p==0){
    brz = gru_b[U_+j]; brr = gru_b[U_+H_+j]; brh = gru_b[U_+2*H_+j];
    // quantize h0 into buffer 0
    float qf = fmaxf(-127.f, fminf(127.f, rintf(hj*inv_sh)));
    ((signed char*)hq[0])[j] = (signed char)(int)qf;
  }
  int len = lens[b];
  const float* xbase = xproj + (size_t)b*G_*U_;
  float xpz=0.f, xpr=0.f, xph=0.f;
  if (p==0){
    xpz = xbase[j]; xpr = xbase[H_+j]; xph = xbase[2*H_+j];
  }
  __syncthreads();

  for (int g=0; g<len; g++){
    // prefetch next step's x (consumed next iteration)
    float nxz=0.f, nxr=0.f, nxh=0.f;
    if (p==0 && (g+1 < len)){
      const float* xn = xbase + (size_t)(g+1)*U_;
      nxz = xn[j]; nxr = xn[H_+j]; nxh = xn[2*H_+j];
    }
    const int4* hc = (const int4*)hq[g&1] + p*8;   // this half's 32 dwords
    int az=0, ar=0, ah=0;
    #pragma unroll
    for (int c=0;c<8;c++){
      int4 hv = hc[c];                              // broadcast ds_read_b128
      az=sdot4(hv.x,wq0[4*c+0],az); ar=sdot4(hv.x,wq1[4*c+0],ar); ah=sdot4(hv.x,wq2[4*c+0],ah);
      az=sdot4(hv.y,wq0[4*c+1],az); ar=sdot4(hv.y,wq1[4*c+1],ar); ah=sdot4(hv.y,wq2[4*c+1],ah);
      az=sdot4(hv.z,wq0[4*c+2],az); ar=sdot4(hv.z,wq1[4*c+2],ar); ah=sdot4(hv.z,wq2[4*c+2],ah);
      az=sdot4(hv.w,wq0[4*c+3],az); ar=sdot4(hv.w,wq1[4*c+3],ar); ah=sdot4(hv.w,wq2[4*c+3],ah);
    }
    if (p){ parti[0][j]=az; parti[1][j]=ar; parti[2][j]=ah; }
    __syncthreads();
    if (p==0){
      float z    = sigmoidf_(xpz + brz + fz*(float)(az + parti[0][j]));
      float r    = sigmoidf_(xpr + brr + fr*(float)(ar + parti[1][j]));
      float cand = tanhf_(xph + r*(brh + fh*(float)(ah + parti[2][j])));
      hj = z*hj + (1.0f-z)*cand;
      float qf = fmaxf(-127.f, fminf(127.f, rintf(hj*inv_sh)));
      ((signed char*)hq[(g+1)&1])[j] = (signed char)(int)qf;
    }
    __syncthreads();
    xpz = nxz; xpr = nxr; xph = nxh;
  }

  // out = sigmoid(h . outW + outb)
  if (t < H_) red[j] = hj*outW[j];
  __syncthreads();
  for (int st=128;st>0;st>>=1){
    if (t<st) red[t]+=red[t+st];
    __syncthreads();
  }
  if (t==0) out[b] = sigmoidf_(red[0]+outb[0]);
}

extern "C" void kernel_launch(void* const* d_in, const int* in_sizes, int n_in,
                              void* d_out, int out_size, void* d_ws, size_t ws_size,
                              hipStream_t stream) {
  const float* demo   = (const float*)d_in[0];
  const float* times  = (const float*)d_in[1];
  const float* values = (const float*)d_in[2];
  const float* meas   = (const float*)d_in[3];
  const float* grid   = (const float*)d_in[4];
  const float* ksic   = (const float*)d_in[5];
  const float* crossW = (const float*)d_in[6];
  const float* dW1    = (const float*)d_in[7];
  const float* db1    = (const float*)d_in[8];
  const float* dW2    = (const float*)d_in[9];
  const float* db2    = (const float*)d_in[10];
  const float* gWx    = (const float*)d_in[11];
  const float* gWh    = (const float*)d_in[12];
  const float* gb     = (const float*)d_in[13];
  const float* outW   = (const float*)d_in[14];
  const float* outb   = (const float*)d_in[15];
  const int*   lens   = (const int*)d_in[16];
  float* out = (float*)d_out;

  float* ws   = (float*)d_ws;
  float* y    = ws;                        // B*D*G
  float* w    = y    + B_*D_*G_;
  float* ytr  = w    + B_*D_*G_;
  float* mean = ytr  + B_*D_*G_;
  float* h0   = mean + B_*D_;
  float* xprj = h0   + B_*H_;              // B*G*768

  k_interp<<<B_*D_, 256, 0, stream>>>(times, values, meas, grid, ksic, y, w, ytr, mean);
  k_demo  <<<1,     256, 0, stream>>>(demo, dW1, db1, dW2, db2, h0);
  k_cross <<<B_*G_, 256, 0, stream>>>(y, w, ytr, mean, crossW, gWx, gb, lens, xprj);
  k_gru   <<<B_,    512, 0, stream>>>(gWh, gb, xprj, h0, lens, outW, outb, out);
}